// Round 13
// baseline (154.487 us; speedup 1.0000x reference)
//
#include <hip/hip_runtime.h>
#include <hip/hip_bf16.h>

// S=8192, D_IN=512, D_OUT=64. O = softmax(tril(QK^T)/8) @ V.
// Round 13: R9 base (best, 133.6us). Single coherent attn change:
//  - split-K parts 512 -> 256 cols (1056 blocks, critical path 8->4 tiles,
//    ~4.1 blocks/CU matches the 4-blocks/CU LDS capacity)
//  - O partials in bf16, lane-linear packed layout (coalesced u32x2 stores);
//    traffic equals R9's fp32@544 despite 2x slots.
// proj byte-exact R9 (R11/R12 proj variants both lost the A/B).

typedef __attribute__((ext_vector_type(8))) short short8;   // 8 bf16 MFMA A/B frag
typedef __attribute__((ext_vector_type(4))) float f32x4;    // MFMA C/D frag
typedef __attribute__((ext_vector_type(4))) float f4v;
typedef __attribute__((ext_vector_type(2))) unsigned int u32x2;

__device__ inline unsigned int pk2(float a, float b) {
    union { __hip_bfloat162 h; unsigned int u; } v;
    v.h = __float22bfloat162_rn(make_float2(a, b));
    return v.u;
}
__device__ inline float bf2f(unsigned int u16) {
    union { float f; unsigned int u; } v;
    v.u = u16 << 16;
    return v.f;
}
__device__ inline void gload_lds16(const void* g, void* l) {
    __builtin_amdgcn_global_load_lds(
        (const __attribute__((address_space(1))) unsigned int*)g,
        (__attribute__((address_space(3))) unsigned int*)l, 16, 0, 0);
}

// Q-blocks of 128 rows, parts of 256 cols. np(qb) = (qb>>1)+1.
// qb = 2a+b: base(qb) = (a+1)*(a+b). Total slots = 1056.
__device__ inline int part_base(int qb) {
    int a = qb >> 1;
    return (a + 1) * (a + (qb & 1));
}

// ---------------- QKV projection (R9 byte-exact) ----------------
// grid (128, 3): x = 64-row block, y = mat. 4 waves, 16 rows each.
__global__ __launch_bounds__(256) void proj_kernel(const float* __restrict__ x,
                                                   const float* __restrict__ wq,
                                                   const float* __restrict__ wk,
                                                   const float* __restrict__ wv,
                                                   unsigned short* __restrict__ qb,
                                                   unsigned short* __restrict__ kb,
                                                   unsigned short* __restrict__ vt) {
    __shared__ unsigned short lds_w[64 * 512];   // 64KB bf16 W_mat, chunk^=(row&7)
    const int tid = threadIdx.x;
    const int wave = tid >> 6, lane = tid & 63;
    const int l16 = lane & 15, quad = lane >> 4;
    const int mat = blockIdx.y;
    const int r0 = blockIdx.x * 64 + wave * 16;
    const float* wm = (mat == 0) ? wq : ((mat == 1) ? wk : wv);

    // stage + convert W_mat: 4096 chunks of 8 bf16 (wave reads one 2KB row: coalesced)
#pragma unroll
    for (int j = 0; j < 16; ++j) {
        const int idx = j * 256 + tid;
        const int row = idx >> 6;
        const int gc = (idx & 63) ^ (row & 7);
        f4v v0 = *(const f4v*)(wm + row * 512 + gc * 8);
        f4v v1 = *(const f4v*)(wm + row * 512 + gc * 8 + 4);
        union { short8 s8; unsigned int u[4]; } pv;
        pv.u[0] = pk2(v0.x, v0.y); pv.u[1] = pk2(v0.z, v0.w);
        pv.u[2] = pk2(v1.x, v1.y); pv.u[3] = pk2(v1.z, v1.w);
        *(short8*)(lds_w + idx * 8) = pv.s8;
    }
    __syncthreads();

    const float* xr = x + (r0 + l16) * 512 + quad * 8;
    f32x4 acc[4] = {};
    for (int kc = 0; kc < 16; ++kc) {
        f4v a0 = *(const f4v*)(xr + kc * 32);
        f4v a1 = *(const f4v*)(xr + kc * 32 + 4);
        union { short8 s8; unsigned int u[4]; } av;
        av.u[0] = pk2(a0.x, a0.y); av.u[1] = pk2(a0.z, a0.w);
        av.u[2] = pk2(a1.x, a1.y); av.u[3] = pk2(a1.z, a1.w);
#pragma unroll
        for (int c = 0; c < 4; ++c) {
            short8 b = *(const short8*)(lds_w + (c * 16 + l16) * 512 +
                                        (((kc * 4 + quad) ^ (l16 & 7)) * 8));
            acc[c] = __builtin_amdgcn_mfma_f32_16x16x32_bf16(av.s8, b, acc[c], 0, 0, 0);
        }
    }
    const float scale = (mat == 0) ? 0.125f : 1.0f;   // fold 1/sqrt(d_k) into Q
#pragma unroll
    for (int c = 0; c < 4; ++c)
#pragma unroll
        for (int r = 0; r < 4; ++r) {
            const int row = r0 + quad * 4 + r;   // C/D: row=(lane>>4)*4+reg, col=lane&15
            const int col = c * 16 + l16;
            union { __hip_bfloat16 h; unsigned short u; } hv;
            hv.h = __float2bfloat16(acc[c][r] * scale);
            if (mat == 0)       qb[row * 64 + col] = hv.u;
            else if (mat == 1)  kb[row * 64 + col] = hv.u;
            else                vt[col * 8192 + row] = hv.u;   // V^T [64][8192]
        }
}

// ---------------- staged split-K flash attention (R9 body, 256-col parts) ----------------
// grid (32, 64), 256 thr. blockIdx.y = qb (128 Q rows), x = part (256 cols).
__global__ __launch_bounds__(256) void attn_kernel(const unsigned short* __restrict__ qbuf,
                                                   const unsigned short* __restrict__ kbuf,
                                                   const unsigned short* __restrict__ vt,
                                                   unsigned short* __restrict__ O_part,
                                                   float* __restrict__ l_part) {
    const int qb_i = blockIdx.y;
    const int part = blockIdx.x;
    const int a = qb_i >> 1;
    if (part > a) return;                         // np = a+1; block-uniform exit

    __shared__ unsigned short lds_k[64 * 64];     // [row][64], chunk^=(row&7)
    __shared__ unsigned short lds_v[64 * 64];     // V^T tile [dim][64], chunk^=(dim&7)
    __shared__ unsigned short lds_p[4][32 * 72];  // per-wave P, stride 72

    const int tid = threadIdx.x;
    const int wave = tid >> 6, lane = tid & 63;
    const int l16 = lane & 15, quad = lane >> 4;
    const int q0 = qb_i * 128;
    const int q0w = q0 + wave * 32;
    const int c0 = part * 256;
    const int cend = min(c0 + 256, q0 + 128);     // 64-aligned
    const int ntiles = (cend - c0) >> 6;          // 2 or 4
    unsigned short* lp = lds_p[wave];

    f32x4 o[2][4] = {};
    float ls[2] = {0.f, 0.f};

    short8 qf[2][2];
#pragma unroll
    for (int cg = 0; cg < 2; ++cg)
#pragma unroll
        for (int kg = 0; kg < 2; ++kg)
            qf[cg][kg] = *(const short8*)(qbuf + (q0w + cg * 16 + l16) * 64 + kg * 32 + quad * 8);

    for (int it = 0; it < ntiles; ++it) {
        const int kc0 = c0 + it * 64;
#pragma unroll
        for (int s = 0; s < 2; ++s) {
            const int idx = (wave * 2 + s) * 64 + lane;   // 0..511
            const int srow = idx >> 3;
            const int scc = (idx & 7) ^ (srow & 7);
            gload_lds16(kbuf + (kc0 + srow) * 64 + scc * 8, lds_k + idx * 8);
            gload_lds16(vt + srow * 8192 + kc0 + scc * 8,   lds_v + idx * 8);
        }
        __syncthreads();

        if (kc0 <= q0w + 31) {                    // wave-uniform compute guard
            short8 af[4][2], vf[4][2];
#pragma unroll
            for (int rg = 0; rg < 4; ++rg)
#pragma unroll
                for (int kg = 0; kg < 2; ++kg)
                    af[rg][kg] = *(const short8*)(lds_k + (rg * 16 + l16) * 64 +
                                                  (((kg * 4 + quad) ^ (l16 & 7)) * 8));
#pragma unroll
            for (int ng = 0; ng < 4; ++ng)
#pragma unroll
                for (int kg = 0; kg < 2; ++kg)
                    vf[ng][kg] = *(const short8*)(lds_v + (ng * 16 + l16) * 64 +
                                                  (((kg * 4 + quad) ^ (l16 & 7)) * 8));

            // S^T = K Q^T: row=K-col kc0+rg*16+quad*4+r, col=Q-row q0w+cg*16+l16
            f32x4 st[4][2];
#pragma unroll
            for (int rg = 0; rg < 4; ++rg)
#pragma unroll
                for (int cg = 0; cg < 2; ++cg) {
                    f32x4 z = {};
                    z          = __builtin_amdgcn_mfma_f32_16x16x32_bf16(af[rg][0], qf[cg][0], z, 0, 0, 0);
                    st[rg][cg] = __builtin_amdgcn_mfma_f32_16x16x32_bf16(af[rg][1], qf[cg][1], z, 0, 0, 0);
                }

            if (kc0 + 63 > q0w) {                 // diagonal tiles only
#pragma unroll
                for (int rg = 0; rg < 4; ++rg)
#pragma unroll
                    for (int cg = 0; cg < 2; ++cg)
#pragma unroll
                        for (int r = 0; r < 4; ++r) {
                            const int kcol = kc0 + rg * 16 + quad * 4 + r;
                            const int qrow = q0w + cg * 16 + l16;
                            if (kcol > qrow) st[rg][cg][r] = -3.0e38f;
                        }
            }

            // p = exp(s), no max subtraction (r3-validated)
#pragma unroll
            for (int rg = 0; rg < 4; ++rg)
#pragma unroll
                for (int cg = 0; cg < 2; ++cg)
#pragma unroll
                    for (int r = 0; r < 4; ++r) {
                        const float p = __expf(st[rg][cg][r]);
                        st[rg][cg][r] = p;
                        ls[cg] += p;
                    }

            // P -> per-wave LDS, stride 72 (wave-synchronous)
#pragma unroll
            for (int rg = 0; rg < 4; ++rg)
#pragma unroll
                for (int cg = 0; cg < 2; ++cg) {
                    u32x2 w;
                    w.x = pk2(st[rg][cg][0], st[rg][cg][1]);
                    w.y = pk2(st[rg][cg][2], st[rg][cg][3]);
                    *(u32x2*)(lp + (cg * 16 + l16) * 72 + rg * 16 + quad * 4) = w;
                }
            asm volatile("s_waitcnt lgkmcnt(0)" ::: "memory");
            short8 pa[2][2];
#pragma unroll
            for (int mg = 0; mg < 2; ++mg)
#pragma unroll
                for (int kg = 0; kg < 2; ++kg)
                    pa[mg][kg] = *(const short8*)(lp + (mg * 16 + l16) * 72 + kg * 32 + quad * 8);

#pragma unroll
            for (int mg = 0; mg < 2; ++mg)
#pragma unroll
                for (int ng = 0; ng < 4; ++ng) {
                    o[mg][ng] = __builtin_amdgcn_mfma_f32_16x16x32_bf16(pa[mg][0], vf[ng][0], o[mg][ng], 0, 0, 0);
                    o[mg][ng] = __builtin_amdgcn_mfma_f32_16x16x32_bf16(pa[mg][1], vf[ng][1], o[mg][ng], 0, 0, 0);
                }
        }
        __syncthreads();
    }

#pragma unroll
    for (int cg = 0; cg < 2; ++cg) {
        ls[cg] += __shfl_xor(ls[cg], 16, 64);
        ls[cg] += __shfl_xor(ls[cg], 32, 64);
    }

    // bf16 packed partial store: unit i = (w2*4+ng)*64+lane holds r=0..3
    // (w2 = wave*2+mg). Lane-stride 8B -> coalesced u32x2 nt stores.
    const int slot = part_base(qb_i) + part;
    unsigned short* Op = O_part + (size_t)slot * 8192;
#pragma unroll
    for (int mg = 0; mg < 2; ++mg)
#pragma unroll
        for (int ng = 0; ng < 4; ++ng) {
            const int i = ((wave * 2 + mg) * 4 + ng) * 64 + lane;
            u32x2 w;
            w.x = pk2(o[mg][ng][0], o[mg][ng][1]);
            w.y = pk2(o[mg][ng][2], o[mg][ng][3]);
            __builtin_nontemporal_store(w, (u32x2*)Op + i);
        }
    if (quad == 0) {
#pragma unroll
        for (int cg = 0; cg < 2; ++cg)
            __builtin_nontemporal_store(ls[cg],
                l_part + slot * 128 + wave * 32 + cg * 16 + l16);
    }
}

// ---------------- combine: sum bf16 partials, normalize ----------------
// grid 256: block = qb*4 + q4; q4 covers w2 in {2q4, 2q4+1} (rows q4*32..+31).
__global__ __launch_bounds__(256) void attn_reduce_kernel(const unsigned short* __restrict__ O_part,
                                                          const float* __restrict__ l_part,
                                                          float* __restrict__ out) {
    __shared__ float Ls[32];
    const int qb_i = blockIdx.x >> 2;
    const int q4 = blockIdx.x & 3;
    const int t = threadIdx.x;
    const int np = (qb_i >> 1) + 1;
    const int base = part_base(qb_i);

    if (t < 32) {
        float s = 0.0f;
        for (int p = 0; p < np; ++p)
            s += __builtin_nontemporal_load(l_part + (base + p) * 128 + q4 * 32 + t);
        Ls[t] = s;
    }
    __syncthreads();

#pragma unroll
    for (int u = 0; u < 2; ++u) {
        const int j = u * 256 + t;                // 0..511 local units
        const int w2 = 2 * q4 + (j >> 8);
        const int ng = (j >> 6) & 3;
        const int lane = j & 63;
        const int i = (w2 * 4 + ng) * 64 + lane;  // global unit in slot
        float acc[4] = {0.f, 0.f, 0.f, 0.f};
        for (int p = 0; p < np; ++p) {
            u32x2 v = __builtin_nontemporal_load(
                (const u32x2*)(O_part + (size_t)(base + p) * 8192) + i);
            acc[0] += bf2f(v.x & 0xffffu);
            acc[1] += bf2f(v.x >> 16);
            acc[2] += bf2f(v.y & 0xffffu);
            acc[3] += bf2f(v.y >> 16);
        }
        const int quad = lane >> 4, l16 = lane & 15;
#pragma unroll
        for (int r = 0; r < 4; ++r) {
            const int lrow = (w2 - 2 * q4) * 16 + quad * 4 + r;   // 0..31
            out[((size_t)qb_i * 128 + w2 * 16 + quad * 4 + r) * 64 + ng * 16 + l16] =
                acc[r] / Ls[lrow];
        }
    }
}

extern "C" void kernel_launch(void* const* d_in, const int* in_sizes, int n_in,
                              void* d_out, int out_size, void* d_ws, size_t ws_size,
                              hipStream_t stream) {
    const float* x  = (const float*)d_in[0];
    const float* wq = (const float*)d_in[1];
    const float* wk = (const float*)d_in[2];
    const float* wv = (const float*)d_in[3];
    float* out = (float*)d_out;

    char* ws = (char*)d_ws;
    unsigned short* qb = (unsigned short*)(ws);               // 1,048,576 B
    unsigned short* kb = (unsigned short*)(ws + 1048576);     // 1,048,576 B
    unsigned short* vt = (unsigned short*)(ws + 2097152);     // 1,048,576 B (V^T [64][8192])
    unsigned short* O_part = (unsigned short*)(ws + 3145728); // 1056*8192*2 = 17,301,504 B
    float* l_part = (float*)(ws + 20447232);                  // 1056*128*4 = 540,672 B
    // total ws: 20,987,904 B

    proj_kernel<<<dim3(128, 3), 256, 0, stream>>>(x, wq, wk, wv, qb, kb, vt);
    attn_kernel<<<dim3(32, 64), 256, 0, stream>>>(qb, kb, vt, O_part, l_part);
    attn_reduce_kernel<<<256, 256, 0, stream>>>(O_part, l_part, out);
}

// Round 14
// 122.333 us; speedup vs baseline: 1.2628x; 1.2628x over previous
//
#include <hip/hip_runtime.h>
#include <hip/hip_bf16.h>

// S=8192, D_IN=512, D_OUT=64. O = softmax(tril(QK^T)/8) @ V.
// Round 14: R9 proj + R9 attn byte-exact (best validated, 133.6us total).
// Reduce rebuilt for latency hiding: 512 blocks (2/CU), 1 f4v per thread,
// p-loop unrolled x4 with independent accumulators, plain coalesced loads.
// (R13 showed reduce was ~44us latency-bound at 256 blocks / serial np chain.)

typedef __attribute__((ext_vector_type(8))) short short8;   // 8 bf16 MFMA A/B frag
typedef __attribute__((ext_vector_type(4))) float f32x4;    // MFMA C/D frag
typedef __attribute__((ext_vector_type(4))) float f4v;
typedef __attribute__((ext_vector_type(2))) unsigned int u32x2;

__device__ inline unsigned int pk2(float a, float b) {
    union { __hip_bfloat162 h; unsigned int u; } v;
    v.h = __float22bfloat162_rn(make_float2(a, b));
    return v.u;
}
__device__ inline void gload_lds16(const void* g, void* l) {
    __builtin_amdgcn_global_load_lds(
        (const __attribute__((address_space(1))) unsigned int*)g,
        (__attribute__((address_space(3))) unsigned int*)l, 16, 0, 0);
}

// Q-blocks of 128 rows, parts of 512 cols: np(qb) = (qb>>2)+1.
// base(qb) = qb + 2g(g-1) + (qb&3)*g, g = qb>>2. Total slots = 544.
__device__ inline int part_base(int qb) {
    int g = qb >> 2;
    return qb + 2 * g * (g - 1) + (qb & 3) * g;
}

// ---------------- QKV projection (R9 byte-exact) ----------------
// grid (128, 3): x = 64-row block, y = mat. 4 waves, 16 rows each.
__global__ __launch_bounds__(256) void proj_kernel(const float* __restrict__ x,
                                                   const float* __restrict__ wq,
                                                   const float* __restrict__ wk,
                                                   const float* __restrict__ wv,
                                                   unsigned short* __restrict__ qb,
                                                   unsigned short* __restrict__ kb,
                                                   unsigned short* __restrict__ vt) {
    __shared__ unsigned short lds_w[64 * 512];   // 64KB bf16 W_mat, chunk^=(row&7)
    const int tid = threadIdx.x;
    const int wave = tid >> 6, lane = tid & 63;
    const int l16 = lane & 15, quad = lane >> 4;
    const int mat = blockIdx.y;
    const int r0 = blockIdx.x * 64 + wave * 16;
    const float* wm = (mat == 0) ? wq : ((mat == 1) ? wk : wv);

    // stage + convert W_mat: 4096 chunks of 8 bf16
#pragma unroll
    for (int j = 0; j < 16; ++j) {
        const int idx = j * 256 + tid;
        const int row = idx >> 6;
        const int gc = (idx & 63) ^ (row & 7);
        f4v v0 = *(const f4v*)(wm + row * 512 + gc * 8);
        f4v v1 = *(const f4v*)(wm + row * 512 + gc * 8 + 4);
        union { short8 s8; unsigned int u[4]; } pv;
        pv.u[0] = pk2(v0.x, v0.y); pv.u[1] = pk2(v0.z, v0.w);
        pv.u[2] = pk2(v1.x, v1.y); pv.u[3] = pk2(v1.z, v1.w);
        *(short8*)(lds_w + idx * 8) = pv.s8;
    }
    __syncthreads();

    const float* xr = x + (r0 + l16) * 512 + quad * 8;
    f32x4 acc[4] = {};
    for (int kc = 0; kc < 16; ++kc) {
        f4v a0 = *(const f4v*)(xr + kc * 32);
        f4v a1 = *(const f4v*)(xr + kc * 32 + 4);
        union { short8 s8; unsigned int u[4]; } av;
        av.u[0] = pk2(a0.x, a0.y); av.u[1] = pk2(a0.z, a0.w);
        av.u[2] = pk2(a1.x, a1.y); av.u[3] = pk2(a1.z, a1.w);
#pragma unroll
        for (int c = 0; c < 4; ++c) {
            short8 b = *(const short8*)(lds_w + (c * 16 + l16) * 512 +
                                        (((kc * 4 + quad) ^ (l16 & 7)) * 8));
            acc[c] = __builtin_amdgcn_mfma_f32_16x16x32_bf16(av.s8, b, acc[c], 0, 0, 0);
        }
    }
    const float scale = (mat == 0) ? 0.125f : 1.0f;   // fold 1/sqrt(d_k) into Q
#pragma unroll
    for (int c = 0; c < 4; ++c)
#pragma unroll
        for (int r = 0; r < 4; ++r) {
            const int row = r0 + quad * 4 + r;   // C/D: row=(lane>>4)*4+reg, col=lane&15
            const int col = c * 16 + l16;
            union { __hip_bfloat16 h; unsigned short u; } hv;
            hv.h = __float2bfloat16(acc[c][r] * scale);
            if (mat == 0)       qb[row * 64 + col] = hv.u;
            else if (mat == 1)  kb[row * 64 + col] = hv.u;
            else                vt[col * 8192 + row] = hv.u;   // V^T [64][8192]
        }
}

// ---------------- staged split-K flash attention (R9 byte-exact) ----------------
// grid (16, 64), 256 thr. blockIdx.y = qb (128 Q rows), x = part (512 cols).
__global__ __launch_bounds__(256) void attn_kernel(const unsigned short* __restrict__ qbuf,
                                                   const unsigned short* __restrict__ kbuf,
                                                   const unsigned short* __restrict__ vt,
                                                   float* __restrict__ O_part,
                                                   float* __restrict__ l_part) {
    const int qb_i = blockIdx.y;
    const int part = blockIdx.x;
    const int g = qb_i >> 2;
    if (part > g) return;                         // np = g+1; block-uniform exit

    __shared__ unsigned short lds_k[64 * 64];     // [row][64], chunk^=(row&7)
    __shared__ unsigned short lds_v[64 * 64];     // V^T tile [dim][64], chunk^=(dim&7)
    __shared__ unsigned short lds_p[4][32 * 72];  // per-wave P, stride 72

    const int tid = threadIdx.x;
    const int wave = tid >> 6, lane = tid & 63;
    const int l16 = lane & 15, quad = lane >> 4;
    const int q0 = qb_i * 128;
    const int q0w = q0 + wave * 32;
    const int c0 = part * 512;
    const int cend = min(c0 + 512, q0 + 128);     // 64-aligned
    const int ntiles = (cend - c0) >> 6;
    unsigned short* lp = lds_p[wave];

    f32x4 o[2][4] = {};
    float ls[2] = {0.f, 0.f};

    short8 qf[2][2];
#pragma unroll
    for (int cg = 0; cg < 2; ++cg)
#pragma unroll
        for (int kg = 0; kg < 2; ++kg)
            qf[cg][kg] = *(const short8*)(qbuf + (q0w + cg * 16 + l16) * 64 + kg * 32 + quad * 8);

    for (int it = 0; it < ntiles; ++it) {
        const int kc0 = c0 + it * 64;
#pragma unroll
        for (int s = 0; s < 2; ++s) {
            const int idx = (wave * 2 + s) * 64 + lane;   // 0..511
            const int srow = idx >> 3;
            const int scc = (idx & 7) ^ (srow & 7);
            gload_lds16(kbuf + (kc0 + srow) * 64 + scc * 8, lds_k + idx * 8);
            gload_lds16(vt + srow * 8192 + kc0 + scc * 8,   lds_v + idx * 8);
        }
        __syncthreads();

        if (kc0 <= q0w + 31) {                    // wave-uniform compute guard
            short8 af[4][2], vf[4][2];
#pragma unroll
            for (int rg = 0; rg < 4; ++rg)
#pragma unroll
                for (int kg = 0; kg < 2; ++kg)
                    af[rg][kg] = *(const short8*)(lds_k + (rg * 16 + l16) * 64 +
                                                  (((kg * 4 + quad) ^ (l16 & 7)) * 8));
#pragma unroll
            for (int ng = 0; ng < 4; ++ng)
#pragma unroll
                for (int kg = 0; kg < 2; ++kg)
                    vf[ng][kg] = *(const short8*)(lds_v + (ng * 16 + l16) * 64 +
                                                  (((kg * 4 + quad) ^ (l16 & 7)) * 8));

            // S^T = K Q^T: row=K-col kc0+rg*16+quad*4+r, col=Q-row q0w+cg*16+l16
            f32x4 st[4][2];
#pragma unroll
            for (int rg = 0; rg < 4; ++rg)
#pragma unroll
                for (int cg = 0; cg < 2; ++cg) {
                    f32x4 z = {};
                    z          = __builtin_amdgcn_mfma_f32_16x16x32_bf16(af[rg][0], qf[cg][0], z, 0, 0, 0);
                    st[rg][cg] = __builtin_amdgcn_mfma_f32_16x16x32_bf16(af[rg][1], qf[cg][1], z, 0, 0, 0);
                }

            if (kc0 + 63 > q0w) {                 // diagonal tiles only
#pragma unroll
                for (int rg = 0; rg < 4; ++rg)
#pragma unroll
                    for (int cg = 0; cg < 2; ++cg)
#pragma unroll
                        for (int r = 0; r < 4; ++r) {
                            const int kcol = kc0 + rg * 16 + quad * 4 + r;
                            const int qrow = q0w + cg * 16 + l16;
                            if (kcol > qrow) st[rg][cg][r] = -3.0e38f;
                        }
            }

            // p = exp(s), no max subtraction (r3-validated)
#pragma unroll
            for (int rg = 0; rg < 4; ++rg)
#pragma unroll
                for (int cg = 0; cg < 2; ++cg)
#pragma unroll
                    for (int r = 0; r < 4; ++r) {
                        const float p = __expf(st[rg][cg][r]);
                        st[rg][cg][r] = p;
                        ls[cg] += p;
                    }

            // P -> per-wave LDS, stride 72 (wave-synchronous)
#pragma unroll
            for (int rg = 0; rg < 4; ++rg)
#pragma unroll
                for (int cg = 0; cg < 2; ++cg) {
                    u32x2 w;
                    w.x = pk2(st[rg][cg][0], st[rg][cg][1]);
                    w.y = pk2(st[rg][cg][2], st[rg][cg][3]);
                    *(u32x2*)(lp + (cg * 16 + l16) * 72 + rg * 16 + quad * 4) = w;
                }
            asm volatile("s_waitcnt lgkmcnt(0)" ::: "memory");
            short8 pa[2][2];
#pragma unroll
            for (int mg = 0; mg < 2; ++mg)
#pragma unroll
                for (int kg = 0; kg < 2; ++kg)
                    pa[mg][kg] = *(const short8*)(lp + (mg * 16 + l16) * 72 + kg * 32 + quad * 8);

#pragma unroll
            for (int mg = 0; mg < 2; ++mg)
#pragma unroll
                for (int ng = 0; ng < 4; ++ng) {
                    o[mg][ng] = __builtin_amdgcn_mfma_f32_16x16x32_bf16(pa[mg][0], vf[ng][0], o[mg][ng], 0, 0, 0);
                    o[mg][ng] = __builtin_amdgcn_mfma_f32_16x16x32_bf16(pa[mg][1], vf[ng][1], o[mg][ng], 0, 0, 0);
                }
        }
        __syncthreads();
    }

#pragma unroll
    for (int cg = 0; cg < 2; ++cg) {
        ls[cg] += __shfl_xor(ls[cg], 16, 64);
        ls[cg] += __shfl_xor(ls[cg], 32, 64);
    }

    const int slot = part_base(qb_i) + part;
    float* Op = O_part + (size_t)slot * 8192;
#pragma unroll
    for (int mg = 0; mg < 2; ++mg)
#pragma unroll
        for (int ng = 0; ng < 4; ++ng)
#pragma unroll
            for (int r = 0; r < 4; ++r)
                __builtin_nontemporal_store(o[mg][ng][r],
                    Op + (wave * 32 + mg * 16 + quad * 4 + r) * 64 + ng * 16 + l16);
    if (quad == 0) {
#pragma unroll
        for (int cg = 0; cg < 2; ++cg)
            __builtin_nontemporal_store(ls[cg],
                l_part + slot * 128 + wave * 32 + cg * 16 + l16);
    }
}

// ---------------- combine: parallel sum, latency-hidden ----------------
// grid (8, 64): blockIdx.y = qb, blockIdx.x = c (16-row chunk). 256 thr,
// one f4v per thread; p-loop unrolled x4 into independent accumulators.
__global__ __launch_bounds__(256) void attn_reduce_kernel(const float* __restrict__ O_part,
                                                          const float* __restrict__ l_part,
                                                          float* __restrict__ out) {
    __shared__ float Ls[16];
    const int qb_i = blockIdx.y;
    const int c = blockIdx.x;
    const int t = threadIdx.x;
    const int np = (qb_i >> 2) + 1;
    const int base = part_base(qb_i);

    if (t < 16) {
        float s = 0.0f;
        for (int p = 0; p < np; ++p)
            s += l_part[(base + p) * 128 + c * 16 + t];
        Ls[t] = s;
    }
    __syncthreads();

    const int e = c * 1024 + t * 4;               // element within slot / out tile
    const float* src = O_part + (size_t)base * 8192 + e;

    f4v a0 = {0.f, 0.f, 0.f, 0.f}, a1 = a0, a2 = a0, a3 = a0;
    int p = 0;
    for (; p + 4 <= np; p += 4) {
        a0 += *(const f4v*)(src + (size_t)(p    ) * 8192);
        a1 += *(const f4v*)(src + (size_t)(p + 1) * 8192);
        a2 += *(const f4v*)(src + (size_t)(p + 2) * 8192);
        a3 += *(const f4v*)(src + (size_t)(p + 3) * 8192);
    }
    for (; p < np; ++p)
        a0 += *(const f4v*)(src + (size_t)p * 8192);

    f4v acc = (a0 + a1) + (a2 + a3);
    acc *= (1.0f / Ls[t >> 4]);
    *(f4v*)(out + (size_t)qb_i * 8192 + e) = acc;
}

extern "C" void kernel_launch(void* const* d_in, const int* in_sizes, int n_in,
                              void* d_out, int out_size, void* d_ws, size_t ws_size,
                              hipStream_t stream) {
    const float* x  = (const float*)d_in[0];
    const float* wq = (const float*)d_in[1];
    const float* wk = (const float*)d_in[2];
    const float* wv = (const float*)d_in[3];
    float* out = (float*)d_out;

    char* ws = (char*)d_ws;
    unsigned short* qb = (unsigned short*)(ws);               // 1,048,576 B
    unsigned short* kb = (unsigned short*)(ws + 1048576);     // 1,048,576 B
    unsigned short* vt = (unsigned short*)(ws + 2097152);     // 1,048,576 B (V^T [64][8192])
    float* O_part = (float*)(ws + 3145728);                   // 544*8192*4 = 17,825,792 B
    float* l_part = (float*)(ws + 20971520);                  // 544*128*4 = 278,528 B
    // total ws: 21,250,048 B

    proj_kernel<<<dim3(128, 3), 256, 0, stream>>>(x, wq, wk, wv, qb, kb, vt);
    attn_kernel<<<dim3(16, 64), 256, 0, stream>>>(qb, kb, vt, O_part, l_part);
    attn_reduce_kernel<<<dim3(8, 64), 256, 0, stream>>>(O_part, l_part, out);
}

// Round 15
// 119.195 us; speedup vs baseline: 1.2961x; 1.0263x over previous
//
#include <hip/hip_runtime.h>
#include <hip/hip_bf16.h>

// S=8192, D_IN=512, D_OUT=64. O = softmax(tril(QK^T)/8) @ V.
// Round 15: attn Q-blocks 128 -> 256 rows (8 waves, 512 thr): same 16KB
// staged K/V tile feeds 2x the MFMA work per barrier interval; staging
// traffic halves; 52KB LDS -> 3 blocks/CU = 24 waves/CU. Per-wave math
// byte-identical to R9/R14. proj R14-exact; reduce R14 structure re-indexed.

typedef __attribute__((ext_vector_type(8))) short short8;   // 8 bf16 MFMA A/B frag
typedef __attribute__((ext_vector_type(4))) float f32x4;    // MFMA C/D frag
typedef __attribute__((ext_vector_type(4))) float f4v;
typedef __attribute__((ext_vector_type(2))) unsigned int u32x2;

__device__ inline unsigned int pk2(float a, float b) {
    union { __hip_bfloat162 h; unsigned int u; } v;
    v.h = __float22bfloat162_rn(make_float2(a, b));
    return v.u;
}
__device__ inline void gload_lds16(const void* g, void* l) {
    __builtin_amdgcn_global_load_lds(
        (const __attribute__((address_space(1))) unsigned int*)g,
        (__attribute__((address_space(3))) unsigned int*)l, 16, 0, 0);
}

// Q-blocks of 256 rows (qb in [0,32)), parts of 512 cols. np(qb) = (qb>>1)+1.
// qb = 2a+b: base(qb) = a*a + a + b*(a+1). Total slots = 272.
__device__ inline int part_base(int qb) {
    int a = qb >> 1;
    return a * a + a + (qb & 1) * (a + 1);
}

// ---------------- QKV projection (R9/R14 byte-exact) ----------------
// grid (128, 3): x = 64-row block, y = mat. 4 waves, 16 rows each.
__global__ __launch_bounds__(256) void proj_kernel(const float* __restrict__ x,
                                                   const float* __restrict__ wq,
                                                   const float* __restrict__ wk,
                                                   const float* __restrict__ wv,
                                                   unsigned short* __restrict__ qb,
                                                   unsigned short* __restrict__ kb,
                                                   unsigned short* __restrict__ vt) {
    __shared__ unsigned short lds_w[64 * 512];   // 64KB bf16 W_mat, chunk^=(row&7)
    const int tid = threadIdx.x;
    const int wave = tid >> 6, lane = tid & 63;
    const int l16 = lane & 15, quad = lane >> 4;
    const int mat = blockIdx.y;
    const int r0 = blockIdx.x * 64 + wave * 16;
    const float* wm = (mat == 0) ? wq : ((mat == 1) ? wk : wv);

    // stage + convert W_mat: 4096 chunks of 8 bf16
#pragma unroll
    for (int j = 0; j < 16; ++j) {
        const int idx = j * 256 + tid;
        const int row = idx >> 6;
        const int gc = (idx & 63) ^ (row & 7);
        f4v v0 = *(const f4v*)(wm + row * 512 + gc * 8);
        f4v v1 = *(const f4v*)(wm + row * 512 + gc * 8 + 4);
        union { short8 s8; unsigned int u[4]; } pv;
        pv.u[0] = pk2(v0.x, v0.y); pv.u[1] = pk2(v0.z, v0.w);
        pv.u[2] = pk2(v1.x, v1.y); pv.u[3] = pk2(v1.z, v1.w);
        *(short8*)(lds_w + idx * 8) = pv.s8;
    }
    __syncthreads();

    const float* xr = x + (r0 + l16) * 512 + quad * 8;
    f32x4 acc[4] = {};
    for (int kc = 0; kc < 16; ++kc) {
        f4v a0 = *(const f4v*)(xr + kc * 32);
        f4v a1 = *(const f4v*)(xr + kc * 32 + 4);
        union { short8 s8; unsigned int u[4]; } av;
        av.u[0] = pk2(a0.x, a0.y); av.u[1] = pk2(a0.z, a0.w);
        av.u[2] = pk2(a1.x, a1.y); av.u[3] = pk2(a1.z, a1.w);
#pragma unroll
        for (int c = 0; c < 4; ++c) {
            short8 b = *(const short8*)(lds_w + (c * 16 + l16) * 512 +
                                        (((kc * 4 + quad) ^ (l16 & 7)) * 8));
            acc[c] = __builtin_amdgcn_mfma_f32_16x16x32_bf16(av.s8, b, acc[c], 0, 0, 0);
        }
    }
    const float scale = (mat == 0) ? 0.125f : 1.0f;   // fold 1/sqrt(d_k) into Q
#pragma unroll
    for (int c = 0; c < 4; ++c)
#pragma unroll
        for (int r = 0; r < 4; ++r) {
            const int row = r0 + quad * 4 + r;   // C/D: row=(lane>>4)*4+reg, col=lane&15
            const int col = c * 16 + l16;
            union { __hip_bfloat16 h; unsigned short u; } hv;
            hv.h = __float2bfloat16(acc[c][r] * scale);
            if (mat == 0)       qb[row * 64 + col] = hv.u;
            else if (mat == 1)  kb[row * 64 + col] = hv.u;
            else                vt[col * 8192 + row] = hv.u;   // V^T [64][8192]
        }
}

// ---------------- staged split-K flash attention, 256-row Q-blocks ----------------
// grid (16, 32), 512 thr (8 waves). blockIdx.y = qb (256 rows), x = part (512 cols).
// Wave w: Q rows q0+32w..+31 — per-wave math identical to R9.
__global__ __launch_bounds__(512) void attn_kernel(const unsigned short* __restrict__ qbuf,
                                                   const unsigned short* __restrict__ kbuf,
                                                   const unsigned short* __restrict__ vt,
                                                   float* __restrict__ O_part,
                                                   float* __restrict__ l_part) {
    const int qb_i = blockIdx.y;
    const int part = blockIdx.x;
    const int a = qb_i >> 1;
    if (part > a) return;                         // np = a+1; block-uniform exit

    __shared__ unsigned short lds_k[64 * 64];     // [row][64], chunk^=(row&7)  8KB
    __shared__ unsigned short lds_v[64 * 64];     // V^T tile [dim][64]         8KB
    __shared__ unsigned short lds_p[8][32 * 72];  // per-wave P, stride 72      36KB

    const int tid = threadIdx.x;
    const int wave = tid >> 6, lane = tid & 63;
    const int l16 = lane & 15, quad = lane >> 4;
    const int q0 = qb_i * 256;
    const int q0w = q0 + wave * 32;
    const int c0 = part * 512;
    const int cend = min(c0 + 512, q0 + 256);     // 64-aligned
    const int ntiles = (cend - c0) >> 6;          // 4 or 8
    unsigned short* lp = lds_p[wave];

    f32x4 o[2][4] = {};
    float ls[2] = {0.f, 0.f};

    short8 qf[2][2];
#pragma unroll
    for (int cg = 0; cg < 2; ++cg)
#pragma unroll
        for (int kg = 0; kg < 2; ++kg)
            qf[cg][kg] = *(const short8*)(qbuf + (q0w + cg * 16 + l16) * 64 + kg * 32 + quad * 8);

    // staging decode: one K chunk + one V chunk per thread (512 chunks each)
    const int sidx = tid;
    const int srow = sidx >> 3;
    const int scc = (sidx & 7) ^ (srow & 7);

    for (int it = 0; it < ntiles; ++it) {
        const int kc0 = c0 + it * 64;
        gload_lds16(kbuf + (kc0 + srow) * 64 + scc * 8, lds_k + sidx * 8);
        gload_lds16(vt + srow * 8192 + kc0 + scc * 8,   lds_v + sidx * 8);
        __syncthreads();

        if (kc0 <= q0w + 31) {                    // wave-uniform compute guard
            short8 af[4][2], vf[4][2];
#pragma unroll
            for (int rg = 0; rg < 4; ++rg)
#pragma unroll
                for (int kg = 0; kg < 2; ++kg)
                    af[rg][kg] = *(const short8*)(lds_k + (rg * 16 + l16) * 64 +
                                                  (((kg * 4 + quad) ^ (l16 & 7)) * 8));
#pragma unroll
            for (int ng = 0; ng < 4; ++ng)
#pragma unroll
                for (int kg = 0; kg < 2; ++kg)
                    vf[ng][kg] = *(const short8*)(lds_v + (ng * 16 + l16) * 64 +
                                                  (((kg * 4 + quad) ^ (l16 & 7)) * 8));

            // S^T = K Q^T: row=K-col kc0+rg*16+quad*4+r, col=Q-row q0w+cg*16+l16
            f32x4 st[4][2];
#pragma unroll
            for (int rg = 0; rg < 4; ++rg)
#pragma unroll
                for (int cg = 0; cg < 2; ++cg) {
                    f32x4 z = {};
                    z          = __builtin_amdgcn_mfma_f32_16x16x32_bf16(af[rg][0], qf[cg][0], z, 0, 0, 0);
                    st[rg][cg] = __builtin_amdgcn_mfma_f32_16x16x32_bf16(af[rg][1], qf[cg][1], z, 0, 0, 0);
                }

            if (kc0 + 63 > q0w) {                 // diagonal tiles only
#pragma unroll
                for (int rg = 0; rg < 4; ++rg)
#pragma unroll
                    for (int cg = 0; cg < 2; ++cg)
#pragma unroll
                        for (int r = 0; r < 4; ++r) {
                            const int kcol = kc0 + rg * 16 + quad * 4 + r;
                            const int qrow = q0w + cg * 16 + l16;
                            if (kcol > qrow) st[rg][cg][r] = -3.0e38f;
                        }
            }

            // p = exp(s), no max subtraction (r3-validated)
#pragma unroll
            for (int rg = 0; rg < 4; ++rg)
#pragma unroll
                for (int cg = 0; cg < 2; ++cg)
#pragma unroll
                    for (int r = 0; r < 4; ++r) {
                        const float p = __expf(st[rg][cg][r]);
                        st[rg][cg][r] = p;
                        ls[cg] += p;
                    }

            // P -> per-wave LDS, stride 72 (wave-synchronous)
#pragma unroll
            for (int rg = 0; rg < 4; ++rg)
#pragma unroll
                for (int cg = 0; cg < 2; ++cg) {
                    u32x2 w;
                    w.x = pk2(st[rg][cg][0], st[rg][cg][1]);
                    w.y = pk2(st[rg][cg][2], st[rg][cg][3]);
                    *(u32x2*)(lp + (cg * 16 + l16) * 72 + rg * 16 + quad * 4) = w;
                }
            asm volatile("s_waitcnt lgkmcnt(0)" ::: "memory");
            short8 pa[2][2];
#pragma unroll
            for (int mg = 0; mg < 2; ++mg)
#pragma unroll
                for (int kg = 0; kg < 2; ++kg)
                    pa[mg][kg] = *(const short8*)(lp + (mg * 16 + l16) * 72 + kg * 32 + quad * 8);

#pragma unroll
            for (int mg = 0; mg < 2; ++mg)
#pragma unroll
                for (int ng = 0; ng < 4; ++ng) {
                    o[mg][ng] = __builtin_amdgcn_mfma_f32_16x16x32_bf16(pa[mg][0], vf[ng][0], o[mg][ng], 0, 0, 0);
                    o[mg][ng] = __builtin_amdgcn_mfma_f32_16x16x32_bf16(pa[mg][1], vf[ng][1], o[mg][ng], 0, 0, 0);
                }
        }
        __syncthreads();
    }

#pragma unroll
    for (int cg = 0; cg < 2; ++cg) {
        ls[cg] += __shfl_xor(ls[cg], 16, 64);
        ls[cg] += __shfl_xor(ls[cg], 32, 64);
    }

    const int slot = part_base(qb_i) + part;
    float* Op = O_part + (size_t)slot * 16384;    // 256 rows x 64 cols
#pragma unroll
    for (int mg = 0; mg < 2; ++mg)
#pragma unroll
        for (int ng = 0; ng < 4; ++ng)
#pragma unroll
            for (int r = 0; r < 4; ++r)
                __builtin_nontemporal_store(o[mg][ng][r],
                    Op + (wave * 32 + mg * 16 + quad * 4 + r) * 64 + ng * 16 + l16);
    if (quad == 0) {
#pragma unroll
        for (int cg = 0; cg < 2; ++cg)
            __builtin_nontemporal_store(ls[cg],
                l_part + slot * 256 + wave * 32 + cg * 16 + l16);
    }
}

// ---------------- combine: parallel sum, latency-hidden (R14 structure) ----------------
// grid (16, 32): blockIdx.y = qb, blockIdx.x = c (16-row chunk of 256). 256 thr,
// one f4v per thread; p-loop unrolled x4 into independent accumulators.
__global__ __launch_bounds__(256) void attn_reduce_kernel(const float* __restrict__ O_part,
                                                          const float* __restrict__ l_part,
                                                          float* __restrict__ out) {
    __shared__ float Ls[16];
    const int qb_i = blockIdx.y;
    const int c = blockIdx.x;
    const int t = threadIdx.x;
    const int np = (qb_i >> 1) + 1;
    const int base = part_base(qb_i);

    if (t < 16) {
        float s = 0.0f;
        for (int p = 0; p < np; ++p)
            s += l_part[(base + p) * 256 + c * 16 + t];
        Ls[t] = s;
    }
    __syncthreads();

    const int e = c * 1024 + t * 4;               // element within slot / out tile
    const float* src = O_part + (size_t)base * 16384 + e;

    f4v a0 = {0.f, 0.f, 0.f, 0.f}, a1 = a0, a2 = a0, a3 = a0;
    int p = 0;
    for (; p + 4 <= np; p += 4) {
        a0 += *(const f4v*)(src + (size_t)(p    ) * 16384);
        a1 += *(const f4v*)(src + (size_t)(p + 1) * 16384);
        a2 += *(const f4v*)(src + (size_t)(p + 2) * 16384);
        a3 += *(const f4v*)(src + (size_t)(p + 3) * 16384);
    }
    for (; p < np; ++p)
        a0 += *(const f4v*)(src + (size_t)p * 16384);

    f4v acc = (a0 + a1) + (a2 + a3);
    acc *= (1.0f / Ls[t >> 4]);
    *(f4v*)(out + (size_t)qb_i * 16384 + e) = acc;
}

extern "C" void kernel_launch(void* const* d_in, const int* in_sizes, int n_in,
                              void* d_out, int out_size, void* d_ws, size_t ws_size,
                              hipStream_t stream) {
    const float* x  = (const float*)d_in[0];
    const float* wq = (const float*)d_in[1];
    const float* wk = (const float*)d_in[2];
    const float* wv = (const float*)d_in[3];
    float* out = (float*)d_out;

    char* ws = (char*)d_ws;
    unsigned short* qb = (unsigned short*)(ws);               // 1,048,576 B
    unsigned short* kb = (unsigned short*)(ws + 1048576);     // 1,048,576 B
    unsigned short* vt = (unsigned short*)(ws + 2097152);     // 1,048,576 B (V^T [64][8192])
    float* O_part = (float*)(ws + 3145728);                   // 272*16384*4 = 17,825,792 B
    float* l_part = (float*)(ws + 20971520);                  // 272*256*4 = 278,528 B
    // total ws: 21,250,048 B

    proj_kernel<<<dim3(128, 3), 256, 0, stream>>>(x, wq, wk, wv, qb, kb, vt);
    attn_kernel<<<dim3(16, 32), 512, 0, stream>>>(qb, kb, vt, O_part, l_part);
    attn_reduce_kernel<<<dim3(16, 32), 256, 0, stream>>>(O_part, l_part, out);
}